// Round 1
// baseline (500.863 us; speedup 1.0000x reference)
//
#include <hip/hip_runtime.h>
#include <hip/hip_bf16.h>
#include <cstdint>

#define NPTS (2048 * 192)          // 393216 points
#define TBL  (1u << 19)            // hash table size per level
#define TMASK (TBL - 1u)
#define PBLOCKS (NPTS / 256)       // 1536

// geomspace(16, 2048, 16).astype(int)
__constant__ float LVLS[16] = {16.f, 22.f, 30.f, 42.f, 58.f, 80.f, 111.f, 153.f,
                               212.f, 294.f, 406.f, 561.f, 776.f, 1072.f, 1482.f, 2048.f};

__device__ __forceinline__ uint32_t f2bf(float f) {
    uint32_t u = __float_as_uint(f);
    return (u + 0x7FFFu + ((u >> 16) & 1u)) >> 16;   // RNE bf16
}
__device__ __forceinline__ float bf2f(uint32_t u) { return __uint_as_float(u << 16); }

#if __has_builtin(__builtin_amdgcn_sinf)
#define SIN_REV(x) __builtin_amdgcn_sinf(x)   // sin(2*pi*x)
#define COS_REV(x) __builtin_amdgcn_cosf(x)
#else
#define SIN_REV(x) __sinf(6.28318530717958647f * (x))
#define COS_REV(x) __cosf(6.28318530717958647f * (x))
#endif

// ---------------------------------------------------------------------------
// Kernel 1: hash-grid encode. One thread per (point, level). Gather-bound:
// keep registers tiny so 8 waves/SIMD are resident to hide gather latency.
// Output: feats_ws[lvl][p] = packed (bf16 f0 | bf16 f1 << 16), layout (16, P).
// ---------------------------------------------------------------------------
__global__ __launch_bounds__(256) void k_encode(const float* __restrict__ x,
                                                const float* __restrict__ tables,
                                                uint32_t* __restrict__ feats)
{
    int lvl = blockIdx.x / PBLOCKS;
    int p   = (blockIdx.x - lvl * PBLOCKS) * 256 + threadIdx.x;

    size_t p3 = (size_t)p * 3;
    float s  = LVLS[lvl];
    float px = (x[p3 + 0] + 0.5f) * s;
    float py = (x[p3 + 1] + 0.5f) * s;
    float pz = (x[p3 + 2] + 0.5f) * s;

    float flx = floorf(px), fly = floorf(py), flz = floorf(pz);
    float frx = px - flx,   fry = py - fly,   frz = pz - flz;
    int ix = (int)flx, iy = (int)fly, iz = (int)flz;

    const float2* tb = (const float2*)tables + (size_t)lvl * TBL;

    // compute all 8 hashes first so loads batch up (latency overlap)
    uint32_t h[8];
#pragma unroll
    for (int c = 0; c < 8; ++c) {
        uint32_t cx = (uint32_t)(ix + (c & 1));
        uint32_t cy = (uint32_t)(iy + ((c >> 1) & 1));
        uint32_t cz = (uint32_t)(iz + ((c >> 2) & 1));
        h[c] = (cx * 1u ^ cy * 2654435761u ^ cz * 805459861u) & TMASK;
    }
    float2 v[8];
#pragma unroll
    for (int c = 0; c < 8; ++c) v[c] = tb[h[c]];

    float f0 = 0.f, f1 = 0.f;
#pragma unroll
    for (int c = 0; c < 8; ++c) {
        float w = ((c & 1)        ? frx : 1.f - frx)
                * (((c >> 1) & 1) ? fry : 1.f - fry)
                * (((c >> 2) & 1) ? frz : 1.f - frz);
        f0 += w * v[c].x;
        f1 += w * v[c].y;
    }
    feats[(size_t)lvl * NPTS + p] = f2bf(f0) | (f2bf(f1) << 16);
}

// ---------------------------------------------------------------------------
// Kernel 2: fused MLPs. One thread per point; weights broadcast from LDS
// (wave-uniform addresses -> conflict-free broadcast); activations in regs.
// ---------------------------------------------------------------------------
__global__ __launch_bounds__(256) void k_mlp(const uint32_t* __restrict__ feats,
                                             const float* __restrict__ x,
                                             const float* __restrict__ rdir,
                                             const float* __restrict__ dW1,
                                             const float* __restrict__ db1,
                                             const float* __restrict__ dW2,
                                             const float* __restrict__ db2,
                                             const float* __restrict__ cW1,
                                             const float* __restrict__ cb1,
                                             const float* __restrict__ cW2,
                                             const float* __restrict__ cb2,
                                             const float* __restrict__ cW3,
                                             const float* __restrict__ cb3,
                                             float* __restrict__ out)
{
    constexpr int O_DW1 = 0, O_DB1 = 2048, O_DW2 = 2112, O_DB2 = 3136,
                  O_CW1 = 3152, O_CB1 = 5904, O_CW2 = 5968, O_CB2 = 10064,
                  O_CW3 = 10128, O_CB3 = 10320;
    __shared__ float sW[10324];

    int tid = threadIdx.x;
    for (int i = tid; i < 2048; i += 256) sW[O_DW1 + i] = dW1[i];
    for (int i = tid; i < 1024; i += 256) sW[O_DW2 + i] = dW2[i];
    for (int i = tid; i < 2752; i += 256) sW[O_CW1 + i] = cW1[i];
    for (int i = tid; i < 4096; i += 256) sW[O_CW2 + i] = cW2[i];
    if (tid < 192) sW[O_CW3 + tid] = cW3[tid];
    if (tid < 64)  sW[O_DB1 + tid] = db1[tid];
    if (tid < 16)  sW[O_DB2 + tid] = db2[tid];
    if (tid < 64)  sW[O_CB1 + tid] = cb1[tid];
    if (tid < 64)  sW[O_CB2 + tid] = cb2[tid];
    if (tid < 3)   sW[O_CB3 + tid] = cb3[tid];
    __syncthreads();

    int p = blockIdx.x * 256 + tid;

    // unpack bf16 feats (coalesced: (32, P)-style transposed layout)
    float f[32];
#pragma unroll
    for (int l = 0; l < 16; ++l) {
        uint32_t pk = feats[(size_t)l * NPTS + p];
        f[2 * l]     = bf2f(pk & 0xFFFFu);
        f[2 * l + 1] = bf2f(pk >> 16);
    }

    // ---- density layer 1: (32 -> 64), relu
    float h1[64];
#pragma unroll
    for (int j = 0; j < 64; ++j) h1[j] = sW[O_DB1 + j];
#pragma unroll
    for (int k = 0; k < 32; ++k) {
        float a = f[k];
        const float4* w4 = (const float4*)&sW[O_DW1 + k * 64];
#pragma unroll
        for (int j = 0; j < 16; ++j) {
            float4 w = w4[j];
            h1[4 * j + 0] += a * w.x;
            h1[4 * j + 1] += a * w.y;
            h1[4 * j + 2] += a * w.z;
            h1[4 * j + 3] += a * w.w;
        }
    }
#pragma unroll
    for (int j = 0; j < 64; ++j) h1[j] = fmaxf(h1[j], 0.f);

    // ---- density layer 2: (64 -> 16), linear
    float ls[16];
#pragma unroll
    for (int j = 0; j < 16; ++j) ls[j] = sW[O_DB2 + j];
#pragma unroll
    for (int k = 0; k < 64; ++k) {
        float a = h1[k];
        const float4* w4 = (const float4*)&sW[O_DW2 + k * 16];
#pragma unroll
        for (int j = 0; j < 4; ++j) {
            float4 w = w4[j];
            ls[4 * j + 0] += a * w.x;
            ls[4 * j + 1] += a * w.y;
            ls[4 * j + 2] += a * w.z;
            ls[4 * j + 3] += a * w.w;
        }
    }
    float ls0 = ls[0];

    // ---- color input vector: [log_sigma(16), rd(3), per-dim sin x4, cos x4 (24)]
    float av[43];
#pragma unroll
    for (int j = 0; j < 16; ++j) av[j] = ls[j];
    size_t p3 = (size_t)p * 3;
    float rx = rdir[p3 + 0], ry = rdir[p3 + 1], rz = rdir[p3 + 2];
    av[16] = rx; av[17] = ry; av[18] = rz;
#pragma unroll
    for (int d = 0; d < 3; ++d) {
        float r = (d == 0) ? rx : ((d == 1) ? ry : rz);
#pragma unroll
        for (int l = 0; l < 4; ++l) {
            float rev = r * (float)(1 << l);      // exact pow2 scale
            av[19 + 8 * d + l]     = SIN_REV(rev);
            av[19 + 8 * d + 4 + l] = COS_REV(rev);
        }
    }

    // ---- color layer 1: (43 -> 64), relu
    float c1[64];
#pragma unroll
    for (int j = 0; j < 64; ++j) c1[j] = sW[O_CB1 + j];
#pragma unroll
    for (int k = 0; k < 43; ++k) {
        float a = av[k];
        const float4* w4 = (const float4*)&sW[O_CW1 + k * 64];
#pragma unroll
        for (int j = 0; j < 16; ++j) {
            float4 w = w4[j];
            c1[4 * j + 0] += a * w.x;
            c1[4 * j + 1] += a * w.y;
            c1[4 * j + 2] += a * w.z;
            c1[4 * j + 3] += a * w.w;
        }
    }

    // ---- color layer 2: (64 -> 64), relu folded on input
    float c2[64];
#pragma unroll
    for (int j = 0; j < 64; ++j) c2[j] = sW[O_CB2 + j];
#pragma unroll
    for (int k = 0; k < 64; ++k) {
        float a = fmaxf(c1[k], 0.f);
        const float4* w4 = (const float4*)&sW[O_CW2 + k * 64];
#pragma unroll
        for (int j = 0; j < 16; ++j) {
            float4 w = w4[j];
            c2[4 * j + 0] += a * w.x;
            c2[4 * j + 1] += a * w.y;
            c2[4 * j + 2] += a * w.z;
            c2[4 * j + 3] += a * w.w;
        }
    }

    // ---- color layer 3: (64 -> 3), sigmoid
    float col0 = sW[O_CB3 + 0], col1 = sW[O_CB3 + 1], col2 = sW[O_CB3 + 2];
#pragma unroll
    for (int k = 0; k < 64; ++k) {
        float a = fmaxf(c2[k], 0.f);
        col0 += a * sW[O_CW3 + k * 3 + 0];
        col1 += a * sW[O_CW3 + k * 3 + 1];
        col2 += a * sW[O_CW3 + k * 3 + 2];
    }

    // ---- mask + outputs
    float xfx = x[p3 + 0] + 0.5f;
    float xfy = x[p3 + 1] + 0.5f;
    float xfz = x[p3 + 2] + 0.5f;
    bool m = (xfx > 0.f) && (xfx < 1.f) && (xfy > 0.f) && (xfy < 1.f) &&
             (xfz > 0.f) && (xfz < 1.f);

    float s0 = m ? 1.f / (1.f + __expf(-col0)) : 0.f;
    float s1 = m ? 1.f / (1.f + __expf(-col1)) : 0.f;
    float s2 = m ? 1.f / (1.f + __expf(-col2)) : 0.f;
    float sg = m ? __expf(ls0) : 0.f;

    out[p3 + 0] = s0;
    out[p3 + 1] = s1;
    out[p3 + 2] = s2;
    out[(size_t)3 * NPTS + p] = sg;
}

extern "C" void kernel_launch(void* const* d_in, const int* in_sizes, int n_in,
                              void* d_out, int out_size, void* d_ws, size_t ws_size,
                              hipStream_t stream) {
    const float* x      = (const float*)d_in[0];
    const float* rdir   = (const float*)d_in[1];
    const float* tables = (const float*)d_in[2];
    const float* dW1 = (const float*)d_in[3];
    const float* db1 = (const float*)d_in[4];
    const float* dW2 = (const float*)d_in[5];
    const float* db2 = (const float*)d_in[6];
    const float* cW1 = (const float*)d_in[7];
    const float* cb1 = (const float*)d_in[8];
    const float* cW2 = (const float*)d_in[9];
    const float* cb2 = (const float*)d_in[10];
    const float* cW3 = (const float*)d_in[11];
    const float* cb3 = (const float*)d_in[12];
    float* out = (float*)d_out;

    uint32_t* feats = (uint32_t*)d_ws;   // 16 * NPTS * 4 B = 25.2 MB

    k_encode<<<PBLOCKS * 16, 256, 0, stream>>>(x, tables, feats);
    k_mlp<<<PBLOCKS, 256, 0, stream>>>(feats, x, rdir, dW1, db1, dW2, db2,
                                       cW1, cb1, cW2, cb2, cW3, cb3, out);
}

// Round 2
// 403.353 us; speedup vs baseline: 1.2417x; 1.2417x over previous
//
#include <hip/hip_runtime.h>
#include <hip/hip_bf16.h>
#include <cstdint>

#define NPTS (2048 * 192)          // 393216 points
#define TBL  (1u << 19)            // hash table size per level
#define TMASK (TBL - 1u)
#define PBLOCKS (NPTS / 256)       // 1536

// geomspace(16, 2048, 16).astype(int)
__constant__ float LVLS[16] = {16.f, 22.f, 30.f, 42.f, 58.f, 80.f, 111.f, 153.f,
                               212.f, 294.f, 406.f, 561.f, 776.f, 1072.f, 1482.f, 2048.f};

__device__ __forceinline__ uint32_t f2bf(float f) {
    uint32_t u = __float_as_uint(f);
    return (u + 0x7FFFu + ((u >> 16) & 1u)) >> 16;   // RNE bf16
}
__device__ __forceinline__ float bf2f(uint32_t u) { return __uint_as_float(u << 16); }

#if __has_builtin(__builtin_amdgcn_sinf)
#define SIN_REV(x) __builtin_amdgcn_sinf(x)   // sin(2*pi*x)
#define COS_REV(x) __builtin_amdgcn_cosf(x)
#else
#define SIN_REV(x) __sinf(6.28318530717958647f * (x))
#define COS_REV(x) __cosf(6.28318530717958647f * (x))
#endif

// ---------------------------------------------------------------------------
// Kernel 1: hash-grid encode. One thread per (point, level). Gather-bound.
// (unchanged this round — isolating the k_mlp change)
// ---------------------------------------------------------------------------
__global__ __launch_bounds__(256) void k_encode(const float* __restrict__ x,
                                                const float* __restrict__ tables,
                                                uint32_t* __restrict__ feats)
{
    int lvl = blockIdx.x / PBLOCKS;
    int p   = (blockIdx.x - lvl * PBLOCKS) * 256 + threadIdx.x;

    size_t p3 = (size_t)p * 3;
    float s  = LVLS[lvl];
    float px = (x[p3 + 0] + 0.5f) * s;
    float py = (x[p3 + 1] + 0.5f) * s;
    float pz = (x[p3 + 2] + 0.5f) * s;

    float flx = floorf(px), fly = floorf(py), flz = floorf(pz);
    float frx = px - flx,   fry = py - fly,   frz = pz - flz;
    int ix = (int)flx, iy = (int)fly, iz = (int)flz;

    const float2* tb = (const float2*)tables + (size_t)lvl * TBL;

    uint32_t h[8];
#pragma unroll
    for (int c = 0; c < 8; ++c) {
        uint32_t cx = (uint32_t)(ix + (c & 1));
        uint32_t cy = (uint32_t)(iy + ((c >> 1) & 1));
        uint32_t cz = (uint32_t)(iz + ((c >> 2) & 1));
        h[c] = (cx * 1u ^ cy * 2654435761u ^ cz * 805459861u) & TMASK;
    }
    float2 v[8];
#pragma unroll
    for (int c = 0; c < 8; ++c) v[c] = tb[h[c]];

    float f0 = 0.f, f1 = 0.f;
#pragma unroll
    for (int c = 0; c < 8; ++c) {
        float w = ((c & 1)        ? frx : 1.f - frx)
                * (((c >> 1) & 1) ? fry : 1.f - fry)
                * (((c >> 2) & 1) ? frz : 1.f - frz);
        f0 += w * v[c].x;
        f1 += w * v[c].y;
    }
    feats[(size_t)lvl * NPTS + p] = f2bf(f0) | (f2bf(f1) << 16);
}

// ---------------------------------------------------------------------------
// Kernel 2: fused MLPs. One thread per point. Weights are WAVE-UNIFORM, so
// they go through the scalar path: global loads with compile-time-constant
// indices -> s_load_dwordx16 via K$ -> v_fmac_f32 vD, sW, vA. No LDS at all
// (round-1 counters showed the LDS broadcast pipe was the bottleneck:
// 2528 ds_read_b128/wave shared across 4 SIMDs -> VALUBusy 28%).
// ---------------------------------------------------------------------------
__global__ __launch_bounds__(256) void k_mlp(const uint32_t* __restrict__ feats,
                                             const float* __restrict__ x,
                                             const float* __restrict__ rdir,
                                             const float* __restrict__ dW1,
                                             const float* __restrict__ db1,
                                             const float* __restrict__ dW2,
                                             const float* __restrict__ db2,
                                             const float* __restrict__ cW1,
                                             const float* __restrict__ cb1,
                                             const float* __restrict__ cW2,
                                             const float* __restrict__ cb2,
                                             const float* __restrict__ cW3,
                                             const float* __restrict__ cb3,
                                             float* __restrict__ out)
{
    int p = blockIdx.x * 256 + threadIdx.x;

    // unpack bf16 feats (coalesced: (16, P) packed layout)
    float f[32];
#pragma unroll
    for (int l = 0; l < 16; ++l) {
        uint32_t pk = feats[(size_t)l * NPTS + p];
        f[2 * l]     = bf2f(pk & 0xFFFFu);
        f[2 * l + 1] = bf2f(pk >> 16);
    }

    // ---- density layer 1: (32 -> 64), relu
    float h1[64];
#pragma unroll
    for (int j = 0; j < 64; ++j) h1[j] = db1[j];
#pragma unroll
    for (int k = 0; k < 32; ++k) {
        float a = f[k];
#pragma unroll
        for (int j = 0; j < 64; ++j) h1[j] = fmaf(a, dW1[k * 64 + j], h1[j]);
    }
#pragma unroll
    for (int j = 0; j < 64; ++j) h1[j] = fmaxf(h1[j], 0.f);

    // ---- density layer 2: (64 -> 16), linear
    float ls[16];
#pragma unroll
    for (int j = 0; j < 16; ++j) ls[j] = db2[j];
#pragma unroll
    for (int k = 0; k < 64; ++k) {
        float a = h1[k];
#pragma unroll
        for (int j = 0; j < 16; ++j) ls[j] = fmaf(a, dW2[k * 16 + j], ls[j]);
    }
    float ls0 = ls[0];

    // ---- color input vector: [log_sigma(16), rd(3), per-dim sin x4, cos x4]
    float av[43];
#pragma unroll
    for (int j = 0; j < 16; ++j) av[j] = ls[j];
    size_t p3 = (size_t)p * 3;
    float rx = rdir[p3 + 0], ry = rdir[p3 + 1], rz = rdir[p3 + 2];
    av[16] = rx; av[17] = ry; av[18] = rz;
#pragma unroll
    for (int d = 0; d < 3; ++d) {
        float r = (d == 0) ? rx : ((d == 1) ? ry : rz);
#pragma unroll
        for (int l = 0; l < 4; ++l) {
            float rev = r * (float)(1 << l);      // exact pow2 scale
            av[19 + 8 * d + l]     = SIN_REV(rev);
            av[19 + 8 * d + 4 + l] = COS_REV(rev);
        }
    }

    // ---- color layer 1: (43 -> 64), relu
    float c1[64];
#pragma unroll
    for (int j = 0; j < 64; ++j) c1[j] = cb1[j];
#pragma unroll
    for (int k = 0; k < 43; ++k) {
        float a = av[k];
#pragma unroll
        for (int j = 0; j < 64; ++j) c1[j] = fmaf(a, cW1[k * 64 + j], c1[j]);
    }

    // ---- color layer 2: (64 -> 64), relu folded on input
    float c2[64];
#pragma unroll
    for (int j = 0; j < 64; ++j) c2[j] = cb2[j];
#pragma unroll
    for (int k = 0; k < 64; ++k) {
        float a = fmaxf(c1[k], 0.f);
#pragma unroll
        for (int j = 0; j < 64; ++j) c2[j] = fmaf(a, cW2[k * 64 + j], c2[j]);
    }

    // ---- color layer 3: (64 -> 3), sigmoid
    float col0 = cb3[0], col1 = cb3[1], col2 = cb3[2];
#pragma unroll
    for (int k = 0; k < 64; ++k) {
        float a = fmaxf(c2[k], 0.f);
        col0 = fmaf(a, cW3[k * 3 + 0], col0);
        col1 = fmaf(a, cW3[k * 3 + 1], col1);
        col2 = fmaf(a, cW3[k * 3 + 2], col2);
    }

    // ---- mask + outputs
    float xfx = x[p3 + 0] + 0.5f;
    float xfy = x[p3 + 1] + 0.5f;
    float xfz = x[p3 + 2] + 0.5f;
    bool m = (xfx > 0.f) && (xfx < 1.f) && (xfy > 0.f) && (xfy < 1.f) &&
             (xfz > 0.f) && (xfz < 1.f);

    float s0 = m ? 1.f / (1.f + __expf(-col0)) : 0.f;
    float s1 = m ? 1.f / (1.f + __expf(-col1)) : 0.f;
    float s2 = m ? 1.f / (1.f + __expf(-col2)) : 0.f;
    float sg = m ? __expf(ls0) : 0.f;

    out[p3 + 0] = s0;
    out[p3 + 1] = s1;
    out[p3 + 2] = s2;
    out[(size_t)3 * NPTS + p] = sg;
}

extern "C" void kernel_launch(void* const* d_in, const int* in_sizes, int n_in,
                              void* d_out, int out_size, void* d_ws, size_t ws_size,
                              hipStream_t stream) {
    const float* x      = (const float*)d_in[0];
    const float* rdir   = (const float*)d_in[1];
    const float* tables = (const float*)d_in[2];
    const float* dW1 = (const float*)d_in[3];
    const float* db1 = (const float*)d_in[4];
    const float* dW2 = (const float*)d_in[5];
    const float* db2 = (const float*)d_in[6];
    const float* cW1 = (const float*)d_in[7];
    const float* cb1 = (const float*)d_in[8];
    const float* cW2 = (const float*)d_in[9];
    const float* cb2 = (const float*)d_in[10];
    const float* cW3 = (const float*)d_in[11];
    const float* cb3 = (const float*)d_in[12];
    float* out = (float*)d_out;

    uint32_t* feats = (uint32_t*)d_ws;   // 16 * NPTS * 4 B = 25.2 MB

    k_encode<<<PBLOCKS * 16, 256, 0, stream>>>(x, tables, feats);
    k_mlp<<<PBLOCKS, 256, 0, stream>>>(feats, x, rdir, dW1, db1, dW2, db2,
                                       cW1, cb1, cW2, cb2, cW3, cb3, out);
}